// Round 8
// baseline (374.415 us; speedup 1.0000x reference)
//
#include <hip/hip_runtime.h>
#include <math.h>

#define N_NODES 10000
#define N_EDGES 160000
#define E2 (N_EDGES + N_NODES)
#define HIDDEN 128
#define NHEAD 4
#define NB 32
#define LN_EPS 1e-5f

// flat-tid region boundaries for k_pre
#define T_INPUT (N_NODES * HIDDEN)                 // 1,280,000
#define T_HIST  (T_INPUT + N_EDGES)                // +160,000
#define T_CONV  (T_HIST + 3 * 512 * 128)           // +196,608
#define T_BOUND (T_CONV + N_NODES)                 // +10,000
#define T_TOTAL T_BOUND

typedef __attribute__((ext_vector_type(8))) short bf16x8;
typedef __attribute__((ext_vector_type(4))) float f32x4;

__device__ __forceinline__ unsigned short f2bf(float f) {
    unsigned int u = __float_as_uint(f);
    u += 0x7fffu + ((u >> 16) & 1u);       // RNE
    return (unsigned short)(u >> 16);
}
__device__ __forceinline__ float bf2f_lo(unsigned int u) { return __uint_as_float(u << 16); }
__device__ __forceinline__ float bf2f_hi(unsigned int u) { return __uint_as_float(u & 0xffff0000u); }
__device__ __forceinline__ float lrelu(float t) { return t > 0.f ? t : 0.2f * t; }

// ---------------- fused preamble: input proj + edge hist + weight conv + bounds ----
__global__ __launch_bounds__(256) void k_pre(const float* __restrict__ x,
                                             const float* __restrict__ W,
                                             const float* __restrict__ b,
                                             const int* __restrict__ ei,
                                             const int* __restrict__ batch,
                                             const float* __restrict__ Ws,
                                             float* __restrict__ h,
                                             unsigned short* __restrict__ hb,
                                             int* counts, int* gstart, int* gend,
                                             unsigned short* __restrict__ Btb) {
    int t = blockIdx.x * blockDim.x + threadIdx.x;
    if (t < T_INPUT) {
        int n = t >> 7, c = t & 127;
        float s = b[c];
        #pragma unroll
        for (int k = 0; k < 5; k++) s += x[n * 5 + k] * W[k * HIDDEN + c];
        float r = fmaxf(s, 0.f);
        h[t] = r;
        hb[t] = f2bf(r);
    } else if (t < T_HIST) {
        int e = t - T_INPUT;
        atomicAdd(&counts[ei[N_EDGES + e]], 1);
    } else if (t < T_CONV) {
        int i = t - T_HIST;
        int l = i >> 16, rem = i & 65535;
        int n = rem >> 7, k = rem & 127;
        Btb[i] = f2bf(Ws[l * 65536 + k * 512 + n]);
    } else if (t < T_BOUND) {
        int n = t - T_CONV;
        int bb = batch[n];
        if (n == 0 || batch[n - 1] != bb) gstart[bb] = n;
        if (n == N_NODES - 1 || batch[n + 1] != bb) gend[bb] = n + 1;
    }
}

// ---------------- prefix scan: 4-aligned row starts (deg = counts[n]+1 kept aside) --
__global__ void k_scan(const int* __restrict__ counts, int* rowptr, int* cursor) {
    __shared__ int sums[1024];
    int t = threadIdx.x;
    const int per = 10;
    int base = t * per;
    int loc[per];
    int s = 0;
    for (int i = 0; i < per; i++) {
        int idx = base + i;
        int v = (idx < N_NODES) ? ((counts[idx] + 1 + 3) & ~3) : 0;   // +1 self-loop, pad to 4
        loc[i] = s; s += v;
    }
    sums[t] = s;
    __syncthreads();
    for (int off = 1; off < 1024; off <<= 1) {
        int v = (t >= off) ? sums[t - off] : 0;
        __syncthreads();
        sums[t] += v;
        __syncthreads();
    }
    int prefix = (t > 0) ? sums[t - 1] : 0;
    for (int i = 0; i < per; i++) {
        int idx = base + i;
        if (idx < N_NODES) { int r = prefix + loc[i]; rowptr[idx] = r; cursor[idx] = r; }
    }
    if (t == 1023) rowptr[N_NODES] = sums[1023];
}

__global__ void k_scatter(const int* __restrict__ ei, int* cursor, int* csr_src) {
    int e = blockIdx.x * blockDim.x + threadIdx.x;
    if (e < N_EDGES) {
        int s = ei[e], d = ei[N_EDGES + e];
        int pos = atomicAdd(&cursor[d], 1);
        csr_src[pos] = s;
    } else if (e < E2) {
        int n = e - N_EDGES;
        int pos = atomicAdd(&cursor[n], 1);
        csr_src[pos] = n;
    }
}

// ---------------- MFMA GEMM + fused attention scores -------------------------
__global__ __launch_bounds__(256) void k_gemm_att(const unsigned short* __restrict__ Ab,
                                                  const unsigned short* __restrict__ Bt,
                                                  const float* __restrict__ ws,
                                                  const float* __restrict__ wd,
                                                  unsigned short* __restrict__ Cb,
                                                  float* __restrict__ a_src,
                                                  float* __restrict__ a_dst) {
    int wave = threadIdx.x >> 6, lane = threadIdx.x & 63;
    int q = lane >> 4, u = lane & 15;
    int h = blockIdx.x;
    int rowgrp = wave & 1, colhalf = wave >> 1;
    int mbase = blockIdx.y * 32 + rowgrp * 16;
    int colbase = h * 128 + colhalf * 64;
    int arow = mbase + u;
    if (arow > N_NODES - 1) arow = N_NODES - 1;
    bf16x8 a[4];
    #pragma unroll
    for (int k0 = 0; k0 < 4; k0++)
        a[k0] = *(const bf16x8*)(Ab + (size_t)arow * 128 + k0 * 32 + q * 8);
    f32x4 acc[4];
    #pragma unroll
    for (int nb = 0; nb < 4; nb++) acc[nb] = (f32x4){0.f, 0.f, 0.f, 0.f};
    #pragma unroll
    for (int nb = 0; nb < 4; nb++) {
        const unsigned short* bp = Bt + (size_t)(colbase + nb * 16 + u) * 128 + q * 8;
        #pragma unroll
        for (int k0 = 0; k0 < 4; k0++) {
            bf16x8 bfr = *(const bf16x8*)(bp + k0 * 32);
            acc[nb] = __builtin_amdgcn_mfma_f32_16x16x32_bf16(a[k0], bfr, acc[nb], 0, 0, 0);
        }
    }
    #pragma unroll
    for (int nb = 0; nb < 4; nb++) {
        int col = colbase + nb * 16 + u;
        #pragma unroll
        for (int r = 0; r < 4; r++) {
            int row = mbase + q * 4 + r;
            if (row < N_NODES) Cb[(size_t)row * 512 + col] = f2bf(acc[nb][r]);
        }
    }
    float ps[4] = {}, pd[4] = {};
    #pragma unroll
    for (int nb = 0; nb < 4; nb++) {
        int cl = colhalf * 64 + nb * 16 + u;
        float wsv = ws[h * 128 + cl], wdv = wd[h * 128 + cl];
        #pragma unroll
        for (int r = 0; r < 4; r++) { ps[r] += acc[nb][r] * wsv; pd[r] += acc[nb][r] * wdv; }
    }
    #pragma unroll
    for (int d = 1; d < 16; d <<= 1) {
        #pragma unroll
        for (int r = 0; r < 4; r++) {
            ps[r] += __shfl_xor(ps[r], d);
            pd[r] += __shfl_xor(pd[r], d);
        }
    }
    __shared__ float ls[2][2][16], ldd[2][2][16];
    if (u == 0) {
        #pragma unroll
        for (int r = 0; r < 4; r++) {
            ls[rowgrp][colhalf][q * 4 + r] = ps[r];
            ldd[rowgrp][colhalf][q * 4 + r] = pd[r];
        }
    }
    __syncthreads();
    if (colhalf == 0 && lane < 16) {
        int row = mbase + lane;
        if (row < N_NODES) {
            a_src[row * 4 + h] = ls[rowgrp][0][lane] + ls[rowgrp][1][lane];
            a_dst[row * 4 + h] = ldd[rowgrp][0][lane] + ldd[rowgrp][1][lane];
        }
    }
}

// ---------------- fused aggregate + head-mean + LN + relu + residual (+pool) --------
// One wave per node; edges processed 4 at a time: one uniform int4 index load,
// 4 independent uint4 gathers in flight, one softmax rescale per 4 edges.
__global__ __launch_bounds__(256) void k_agg(const uint4* __restrict__ hb4,
                                             const int* __restrict__ rowptr,
                                             const int* __restrict__ counts,
                                             const int* __restrict__ csr,
                                             const float* __restrict__ a_src,
                                             const float* __restrict__ a_dst,
                                             const float* __restrict__ bias,
                                             const float* __restrict__ lng,
                                             const float* __restrict__ lnb,
                                             float* __restrict__ h,
                                             unsigned short* __restrict__ hbn,
                                             const int* __restrict__ batch,
                                             const int* __restrict__ gstart,
                                             const int* __restrict__ gend,
                                             float* __restrict__ gout,
                                             int last) {
    int wave = threadIdx.x >> 6;
    int lane = threadIdx.x & 63;
    int n = blockIdx.x * 4 + wave;
    if (n >= N_NODES) return;
    int hl = lane >> 4;
    int pos = lane & 15;
    int off = rowptr[n];
    int deg = counts[n] + 1;                    // self-loop included
    float adn = a_dst[n * 4 + hl];
    float m = -INFINITY, denom = 0.f;
    float o[8] = {};
    for (int i = 0; i < deg; i += 4) {
        int4 s4 = *(const int4*)(csr + off + i);  // 16B-aligned (rows padded to 4)
        int rem = deg - i;
        int s0 = s4.x;
        int s1 = (rem > 1) ? s4.y : s0;
        int s2 = (rem > 2) ? s4.z : s0;
        int s3 = (rem > 3) ? s4.w : s0;
        uint4 u0 = hb4[(size_t)s0 * 64 + lane];
        uint4 u1 = hb4[(size_t)s1 * 64 + lane];
        uint4 u2 = hb4[(size_t)s2 * 64 + lane];
        uint4 u3 = hb4[(size_t)s3 * 64 + lane];
        float e0 = lrelu(a_src[s0 * 4 + hl] + adn);
        float e1 = (rem > 1) ? lrelu(a_src[s1 * 4 + hl] + adn) : -INFINITY;
        float e2 = (rem > 2) ? lrelu(a_src[s2 * 4 + hl] + adn) : -INFINITY;
        float e3 = (rem > 3) ? lrelu(a_src[s3 * 4 + hl] + adn) : -INFINITY;
        float nm = fmaxf(fmaxf(fmaxf(e0, e1), fmaxf(e2, e3)), m);
        float sc = __expf(m - nm);               // m=-inf first block -> 0
        float p0 = __expf(e0 - nm);
        float p1 = __expf(e1 - nm);
        float p2 = __expf(e2 - nm);
        float p3 = __expf(e3 - nm);
        denom = denom * sc + ((p0 + p1) + (p2 + p3));
        o[0] = o[0] * sc + p0 * bf2f_lo(u0.x) + p1 * bf2f_lo(u1.x) + p2 * bf2f_lo(u2.x) + p3 * bf2f_lo(u3.x);
        o[1] = o[1] * sc + p0 * bf2f_hi(u0.x) + p1 * bf2f_hi(u1.x) + p2 * bf2f_hi(u2.x) + p3 * bf2f_hi(u3.x);
        o[2] = o[2] * sc + p0 * bf2f_lo(u0.y) + p1 * bf2f_lo(u1.y) + p2 * bf2f_lo(u2.y) + p3 * bf2f_lo(u3.y);
        o[3] = o[3] * sc + p0 * bf2f_hi(u0.y) + p1 * bf2f_hi(u1.y) + p2 * bf2f_hi(u2.y) + p3 * bf2f_hi(u3.y);
        o[4] = o[4] * sc + p0 * bf2f_lo(u0.z) + p1 * bf2f_lo(u1.z) + p2 * bf2f_lo(u2.z) + p3 * bf2f_lo(u3.z);
        o[5] = o[5] * sc + p0 * bf2f_hi(u0.z) + p1 * bf2f_hi(u1.z) + p2 * bf2f_hi(u2.z) + p3 * bf2f_hi(u3.z);
        o[6] = o[6] * sc + p0 * bf2f_lo(u0.w) + p1 * bf2f_lo(u1.w) + p2 * bf2f_lo(u2.w) + p3 * bf2f_lo(u3.w);
        o[7] = o[7] * sc + p0 * bf2f_hi(u0.w) + p1 * bf2f_hi(u1.w) + p2 * bf2f_hi(u2.w) + p3 * bf2f_hi(u3.w);
        m = nm;
    }
    float inv = 1.f / (denom + 1e-16f);
    #pragma unroll
    for (int k = 0; k < 8; k++) o[k] *= inv;
    #pragma unroll
    for (int k = 0; k < 8; k++) {
        o[k] += __shfl_xor(o[k], 16);
        o[k] += __shfl_xor(o[k], 32);
    }
    float v[8], sv = 0.f, sq = 0.f;
    #pragma unroll
    for (int k = 0; k < 8; k++) {
        float b = bias[8 * pos + k];
        v[k] = 0.25f * o[k] + b;
        sv += v[k]; sq += v[k] * v[k];
    }
    #pragma unroll
    for (int d = 8; d > 0; d >>= 1) {
        sv += __shfl_xor(sv, d);
        sq += __shfl_xor(sq, d);
    }
    float mu = sv * (1.f / 128.f);
    float var = sq * (1.f / 128.f) - mu * mu;
    float rs = rsqrtf(var + LN_EPS);
    if (hl == 0) {
        float* hrow = h + (size_t)n * 128 + 8 * pos;
        float4 old0 = *(const float4*)(hrow);
        float4 old1 = *(const float4*)(hrow + 4);
        float r[8];
        #pragma unroll
        for (int k = 0; k < 8; k++) {
            float y = (v[k] - mu) * rs * lng[8 * pos + k] + lnb[8 * pos + k];
            r[k] = fmaxf(y, 0.f);
        }
        float w[8] = {r[0] + old0.x, r[1] + old0.y, r[2] + old0.z, r[3] + old0.w,
                      r[4] + old1.x, r[5] + old1.y, r[6] + old1.z, r[7] + old1.w};
        *(float4*)(hrow) = make_float4(w[0], w[1], w[2], w[3]);
        *(float4*)(hrow + 4) = make_float4(w[4], w[5], w[6], w[7]);
        if (last) {
            int b = batch[n];
            float invc = 1.f / (float)max(gend[b] - gstart[b], 1);
            #pragma unroll
            for (int k = 0; k < 8; k++)
                atomicAdd(&gout[b * 128 + 8 * pos + k], w[k] * invc);
        } else {
            ushort4 p0, p1;
            p0.x = f2bf(w[0]); p0.y = f2bf(w[1]); p0.z = f2bf(w[2]); p0.w = f2bf(w[3]);
            p1.x = f2bf(w[4]); p1.y = f2bf(w[5]); p1.z = f2bf(w[6]); p1.w = f2bf(w[7]);
            unsigned short* hbrow = hbn + (size_t)n * 128 + 8 * pos;
            *(ushort4*)(hbrow) = p0;
            *(ushort4*)(hbrow + 4) = p1;
        }
    }
}

extern "C" void kernel_launch(void* const* d_in, const int* in_sizes, int n_in,
                              void* d_out, int out_size, void* d_ws, size_t ws_size,
                              hipStream_t stream) {
    const float* x      = (const float*)d_in[0];
    const int*   ei     = (const int*)d_in[1];
    const int*   batch  = (const int*)d_in[2];
    const float* node_W = (const float*)d_in[3];
    const float* node_b = (const float*)d_in[4];
    const float* Ws     = (const float*)d_in[5];
    const float* att_s  = (const float*)d_in[6];
    const float* att_d  = (const float*)d_in[7];
    const float* biases = (const float*)d_in[8];
    const float* ln_g   = (const float*)d_in[9];
    const float* ln_b   = (const float*)d_in[10];

    float* out = (float*)d_out;
    float* h = out;
    float* gout = out + (size_t)N_NODES * HIDDEN;

    char* w = (char*)d_ws;
    auto carve = [&](size_t bytes) {
        void* p = (void*)w;
        w += (bytes + 255) & ~(size_t)255;
        return p;
    };
    int* rowptr  = (int*)carve((N_NODES + 1) * sizeof(int));
    int* cursor  = (int*)carve(N_NODES * sizeof(int));
    int* counts  = (int*)carve(N_NODES * sizeof(int));
    int* csr     = (int*)carve((E2 + 4 * N_NODES + 16) * sizeof(int));  // 4-aligned rows
    int* gstart  = (int*)carve(NB * sizeof(int));
    int* gend    = (int*)carve(NB * sizeof(int));
    float* a_src = (float*)carve((size_t)N_NODES * NHEAD * sizeof(float));
    float* a_dst = (float*)carve((size_t)N_NODES * NHEAD * sizeof(float));
    unsigned short* hb  = (unsigned short*)carve((size_t)N_NODES * 512 * sizeof(unsigned short));
    unsigned short* hbx = (unsigned short*)carve((size_t)N_NODES * HIDDEN * sizeof(unsigned short));
    unsigned short* Btb = (unsigned short*)carve((size_t)3 * 512 * 128 * sizeof(unsigned short));

    hipMemsetAsync(counts, 0, N_NODES * sizeof(int), stream);
    hipMemsetAsync(gout, 0, NB * HIDDEN * sizeof(float), stream);

    k_pre<<<(T_TOTAL + 255) / 256, 256, 0, stream>>>(x, node_W, node_b, ei, batch, Ws,
                                                     h, hbx, counts, gstart, gend, Btb);
    k_scan<<<1, 1024, 0, stream>>>(counts, rowptr, cursor);
    k_scatter<<<(E2 + 255) / 256, 256, 0, stream>>>(ei, cursor, csr);

    for (int l = 0; l < 3; l++) {
        k_gemm_att<<<dim3(4, (N_NODES + 31) / 32), 256, 0, stream>>>(
            hbx, Btb + (size_t)l * 512 * 128,
            att_s + l * NHEAD * 128, att_d + l * NHEAD * 128,
            hb, a_src, a_dst);
        k_agg<<<(N_NODES + 3) / 4, 256, 0, stream>>>((const uint4*)hb, rowptr, counts, csr,
                                           a_src, a_dst,
                                           biases + l * HIDDEN, ln_g + l * HIDDEN,
                                           ln_b + l * HIDDEN, h, hbx,
                                           batch, gstart, gend, gout, (l == 2) ? 1 : 0);
    }
}

// Round 9
// 367.997 us; speedup vs baseline: 1.0174x; 1.0174x over previous
//
#include <hip/hip_runtime.h>
#include <math.h>

#define N_NODES 10000
#define N_EDGES 160000
#define E2 (N_EDGES + N_NODES)
#define HIDDEN 128
#define NHEAD 4
#define NB 32
#define LN_EPS 1e-5f

// flat-tid region boundaries for k_pre
#define T_INPUT (N_NODES * HIDDEN)                 // 1,280,000
#define T_HIST  (T_INPUT + N_EDGES)                // +160,000
#define T_CONV  (T_HIST + 3 * 512 * 128)           // +196,608
#define T_BOUND (T_CONV + N_NODES)                 // +10,000
#define T_TOTAL T_BOUND

typedef __attribute__((ext_vector_type(8))) short bf16x8;
typedef __attribute__((ext_vector_type(4))) float f32x4;

__device__ __forceinline__ unsigned short f2bf(float f) {
    unsigned int u = __float_as_uint(f);
    u += 0x7fffu + ((u >> 16) & 1u);       // RNE
    return (unsigned short)(u >> 16);
}
__device__ __forceinline__ float bf2f_lo(unsigned int u) { return __uint_as_float(u << 16); }
__device__ __forceinline__ float bf2f_hi(unsigned int u) { return __uint_as_float(u & 0xffff0000u); }

// ---------------- fused preamble: input proj + edge hist + weight conv + bounds ----
__global__ __launch_bounds__(256) void k_pre(const float* __restrict__ x,
                                             const float* __restrict__ W,
                                             const float* __restrict__ b,
                                             const int* __restrict__ ei,
                                             const int* __restrict__ batch,
                                             const float* __restrict__ Ws,
                                             float* __restrict__ h,
                                             unsigned short* __restrict__ hb,
                                             int* counts, int* gstart, int* gend,
                                             unsigned short* __restrict__ Btb) {
    int t = blockIdx.x * blockDim.x + threadIdx.x;
    if (t < T_INPUT) {
        int n = t >> 7, c = t & 127;
        float s = b[c];
        #pragma unroll
        for (int k = 0; k < 5; k++) s += x[n * 5 + k] * W[k * HIDDEN + c];
        float r = fmaxf(s, 0.f);
        h[t] = r;
        hb[t] = f2bf(r);
    } else if (t < T_HIST) {
        int e = t - T_INPUT;
        atomicAdd(&counts[ei[N_EDGES + e]], 1);
    } else if (t < T_CONV) {
        int i = t - T_HIST;
        int l = i >> 16, rem = i & 65535;
        int n = rem >> 7, k = rem & 127;
        Btb[i] = f2bf(Ws[l * 65536 + k * 512 + n]);
    } else if (t < T_BOUND) {
        int n = t - T_CONV;
        int bb = batch[n];
        if (n == 0 || batch[n - 1] != bb) gstart[bb] = n;
        if (n == N_NODES - 1 || batch[n + 1] != bb) gend[bb] = n + 1;
    }
}

// ---------------- prefix scan: 4-aligned row starts; degree = counts[n]+1 ----------
__global__ void k_scan(const int* __restrict__ counts, int* rowptr, int* cursor) {
    __shared__ int sums[1024];
    int t = threadIdx.x;
    const int per = 10;
    int base = t * per;
    int loc[per];
    int s = 0;
    for (int i = 0; i < per; i++) {
        int idx = base + i;
        int v = (idx < N_NODES) ? ((counts[idx] + 1 + 3) & ~3) : 0;   // +1 self-loop, pad to 4
        loc[i] = s; s += v;
    }
    sums[t] = s;
    __syncthreads();
    for (int off = 1; off < 1024; off <<= 1) {
        int v = (t >= off) ? sums[t - off] : 0;
        __syncthreads();
        sums[t] += v;
        __syncthreads();
    }
    int prefix = (t > 0) ? sums[t - 1] : 0;
    for (int i = 0; i < per; i++) {
        int idx = base + i;
        if (idx < N_NODES) { int r = prefix + loc[i]; rowptr[idx] = r; cursor[idx] = r; }
    }
    if (t == 1023) rowptr[N_NODES] = sums[1023];
}

__global__ void k_scatter(const int* __restrict__ ei, int* cursor, int* csr_src) {
    int e = blockIdx.x * blockDim.x + threadIdx.x;
    if (e < N_EDGES) {
        int s = ei[e], d = ei[N_EDGES + e];
        int pos = atomicAdd(&cursor[d], 1);
        csr_src[pos] = s;
    } else if (e < E2) {
        int n = e - N_EDGES;
        int pos = atomicAdd(&cursor[n], 1);
        csr_src[pos] = n;
    }
}

// ---------------- MFMA GEMM + fused attention scores -------------------------
__global__ __launch_bounds__(256) void k_gemm_att(const unsigned short* __restrict__ Ab,
                                                  const unsigned short* __restrict__ Bt,
                                                  const float* __restrict__ ws,
                                                  const float* __restrict__ wd,
                                                  unsigned short* __restrict__ Cb,
                                                  float* __restrict__ a_src,
                                                  float* __restrict__ a_dst) {
    int wave = threadIdx.x >> 6, lane = threadIdx.x & 63;
    int q = lane >> 4, u = lane & 15;
    int h = blockIdx.x;
    int rowgrp = wave & 1, colhalf = wave >> 1;
    int mbase = blockIdx.y * 32 + rowgrp * 16;
    int colbase = h * 128 + colhalf * 64;
    int arow = mbase + u;
    if (arow > N_NODES - 1) arow = N_NODES - 1;
    bf16x8 a[4];
    #pragma unroll
    for (int k0 = 0; k0 < 4; k0++)
        a[k0] = *(const bf16x8*)(Ab + (size_t)arow * 128 + k0 * 32 + q * 8);
    f32x4 acc[4];
    #pragma unroll
    for (int nb = 0; nb < 4; nb++) acc[nb] = (f32x4){0.f, 0.f, 0.f, 0.f};
    #pragma unroll
    for (int nb = 0; nb < 4; nb++) {
        const unsigned short* bp = Bt + (size_t)(colbase + nb * 16 + u) * 128 + q * 8;
        #pragma unroll
        for (int k0 = 0; k0 < 4; k0++) {
            bf16x8 bfr = *(const bf16x8*)(bp + k0 * 32);
            acc[nb] = __builtin_amdgcn_mfma_f32_16x16x32_bf16(a[k0], bfr, acc[nb], 0, 0, 0);
        }
    }
    #pragma unroll
    for (int nb = 0; nb < 4; nb++) {
        int col = colbase + nb * 16 + u;
        #pragma unroll
        for (int r = 0; r < 4; r++) {
            int row = mbase + q * 4 + r;
            if (row < N_NODES) Cb[(size_t)row * 512 + col] = f2bf(acc[nb][r]);
        }
    }
    float ps[4] = {}, pd[4] = {};
    #pragma unroll
    for (int nb = 0; nb < 4; nb++) {
        int cl = colhalf * 64 + nb * 16 + u;
        float wsv = ws[h * 128 + cl], wdv = wd[h * 128 + cl];
        #pragma unroll
        for (int r = 0; r < 4; r++) { ps[r] += acc[nb][r] * wsv; pd[r] += acc[nb][r] * wdv; }
    }
    #pragma unroll
    for (int d = 1; d < 16; d <<= 1) {
        #pragma unroll
        for (int r = 0; r < 4; r++) {
            ps[r] += __shfl_xor(ps[r], d);
            pd[r] += __shfl_xor(pd[r], d);
        }
    }
    __shared__ float ls[2][2][16], ldd[2][2][16];
    if (u == 0) {
        #pragma unroll
        for (int r = 0; r < 4; r++) {
            ls[rowgrp][colhalf][q * 4 + r] = ps[r];
            ldd[rowgrp][colhalf][q * 4 + r] = pd[r];
        }
    }
    __syncthreads();
    if (colhalf == 0 && lane < 16) {
        int row = mbase + lane;
        if (row < N_NODES) {
            a_src[row * 4 + h] = ls[rowgrp][0][lane] + ls[rowgrp][1][lane];
            a_dst[row * 4 + h] = ldd[rowgrp][0][lane] + ldd[rowgrp][1][lane];
        }
    }
}

// ---------------- fused aggregate + head-mean + LN + relu + residual (+pool) --------
// Round-7 proven edge loop: one gather in flight, shfl index broadcast, VGPR-lean.
__global__ __launch_bounds__(256) void k_agg(const uint4* __restrict__ hb4,
                                             const int* __restrict__ rowptr,
                                             const int* __restrict__ counts,
                                             const int* __restrict__ csr,
                                             const float* __restrict__ a_src,
                                             const float* __restrict__ a_dst,
                                             const float* __restrict__ bias,
                                             const float* __restrict__ lng,
                                             const float* __restrict__ lnb,
                                             float* __restrict__ h,
                                             unsigned short* __restrict__ hbn,
                                             const int* __restrict__ batch,
                                             const int* __restrict__ gstart,
                                             const int* __restrict__ gend,
                                             float* __restrict__ gout,
                                             int last) {
    int wave = threadIdx.x >> 6;
    int lane = threadIdx.x & 63;
    int n = blockIdx.x * 4 + wave;
    if (n >= N_NODES) return;
    int hl = lane >> 4;
    int pos = lane & 15;
    int off = rowptr[n];
    int deg = counts[n] + 1;                    // self-loop included
    float adn = a_dst[n * 4 + hl];
    float m = -INFINITY, denom = 0.f;
    float o[8] = {};
    for (int base = 0; base < deg; base += 64) {
        int cnt = min(64, deg - base);
        int s = (lane < cnt) ? csr[off + base + lane] : 0;
        for (int i = 0; i < cnt; i++) {
            int si = __shfl(s, i);
            float t = a_src[si * 4 + hl] + adn;
            float e = t > 0.f ? t : 0.2f * t;
            float nm = fmaxf(m, e);
            float sc = __expf(m - nm);           // first edge: exp(-inf) = 0
            float p = __expf(e - nm);
            denom = denom * sc + p;
            uint4 u = hb4[(size_t)si * 64 + lane];
            o[0] = o[0] * sc + p * bf2f_lo(u.x);
            o[1] = o[1] * sc + p * bf2f_hi(u.x);
            o[2] = o[2] * sc + p * bf2f_lo(u.y);
            o[3] = o[3] * sc + p * bf2f_hi(u.y);
            o[4] = o[4] * sc + p * bf2f_lo(u.z);
            o[5] = o[5] * sc + p * bf2f_hi(u.z);
            o[6] = o[6] * sc + p * bf2f_lo(u.w);
            o[7] = o[7] * sc + p * bf2f_hi(u.w);
            m = nm;
        }
    }
    float inv = 1.f / (denom + 1e-16f);
    #pragma unroll
    for (int k = 0; k < 8; k++) o[k] *= inv;
    #pragma unroll
    for (int k = 0; k < 8; k++) {
        o[k] += __shfl_xor(o[k], 16);
        o[k] += __shfl_xor(o[k], 32);
    }
    float v[8], sv = 0.f, sq = 0.f;
    #pragma unroll
    for (int k = 0; k < 8; k++) {
        float b = bias[8 * pos + k];
        v[k] = 0.25f * o[k] + b;
        sv += v[k]; sq += v[k] * v[k];
    }
    #pragma unroll
    for (int d = 8; d > 0; d >>= 1) {
        sv += __shfl_xor(sv, d);
        sq += __shfl_xor(sq, d);
    }
    float mu = sv * (1.f / 128.f);
    float var = sq * (1.f / 128.f) - mu * mu;
    float rs = rsqrtf(var + LN_EPS);
    if (hl == 0) {
        float* hrow = h + (size_t)n * 128 + 8 * pos;
        float4 old0 = *(const float4*)(hrow);
        float4 old1 = *(const float4*)(hrow + 4);
        float r[8];
        #pragma unroll
        for (int k = 0; k < 8; k++) {
            float y = (v[k] - mu) * rs * lng[8 * pos + k] + lnb[8 * pos + k];
            r[k] = fmaxf(y, 0.f);
        }
        float w[8] = {r[0] + old0.x, r[1] + old0.y, r[2] + old0.z, r[3] + old0.w,
                      r[4] + old1.x, r[5] + old1.y, r[6] + old1.z, r[7] + old1.w};
        *(float4*)(hrow) = make_float4(w[0], w[1], w[2], w[3]);
        *(float4*)(hrow + 4) = make_float4(w[4], w[5], w[6], w[7]);
        if (last) {
            int b = batch[n];
            float invc = 1.f / (float)max(gend[b] - gstart[b], 1);
            #pragma unroll
            for (int k = 0; k < 8; k++)
                atomicAdd(&gout[b * 128 + 8 * pos + k], w[k] * invc);
        } else {
            ushort4 p0, p1;
            p0.x = f2bf(w[0]); p0.y = f2bf(w[1]); p0.z = f2bf(w[2]); p0.w = f2bf(w[3]);
            p1.x = f2bf(w[4]); p1.y = f2bf(w[5]); p1.z = f2bf(w[6]); p1.w = f2bf(w[7]);
            unsigned short* hbrow = hbn + (size_t)n * 128 + 8 * pos;
            *(ushort4*)(hbrow) = p0;
            *(ushort4*)(hbrow + 4) = p1;
        }
    }
}

extern "C" void kernel_launch(void* const* d_in, const int* in_sizes, int n_in,
                              void* d_out, int out_size, void* d_ws, size_t ws_size,
                              hipStream_t stream) {
    const float* x      = (const float*)d_in[0];
    const int*   ei     = (const int*)d_in[1];
    const int*   batch  = (const int*)d_in[2];
    const float* node_W = (const float*)d_in[3];
    const float* node_b = (const float*)d_in[4];
    const float* Ws     = (const float*)d_in[5];
    const float* att_s  = (const float*)d_in[6];
    const float* att_d  = (const float*)d_in[7];
    const float* biases = (const float*)d_in[8];
    const float* ln_g   = (const float*)d_in[9];
    const float* ln_b   = (const float*)d_in[10];

    float* out = (float*)d_out;
    float* h = out;
    float* gout = out + (size_t)N_NODES * HIDDEN;

    char* w = (char*)d_ws;
    auto carve = [&](size_t bytes) {
        void* p = (void*)w;
        w += (bytes + 255) & ~(size_t)255;
        return p;
    };
    int* rowptr  = (int*)carve((N_NODES + 1) * sizeof(int));
    int* cursor  = (int*)carve(N_NODES * sizeof(int));
    int* counts  = (int*)carve(N_NODES * sizeof(int));
    int* csr     = (int*)carve((E2 + 4 * N_NODES + 16) * sizeof(int));  // 4-aligned rows
    int* gstart  = (int*)carve(NB * sizeof(int));
    int* gend    = (int*)carve(NB * sizeof(int));
    float* a_src = (float*)carve((size_t)N_NODES * NHEAD * sizeof(float));
    float* a_dst = (float*)carve((size_t)N_NODES * NHEAD * sizeof(float));
    unsigned short* hb  = (unsigned short*)carve((size_t)N_NODES * 512 * sizeof(unsigned short));
    unsigned short* hbx = (unsigned short*)carve((size_t)N_NODES * HIDDEN * sizeof(unsigned short));
    unsigned short* Btb = (unsigned short*)carve((size_t)3 * 512 * 128 * sizeof(unsigned short));

    hipMemsetAsync(counts, 0, N_NODES * sizeof(int), stream);
    hipMemsetAsync(gout, 0, NB * HIDDEN * sizeof(float), stream);

    k_pre<<<(T_TOTAL + 255) / 256, 256, 0, stream>>>(x, node_W, node_b, ei, batch, Ws,
                                                     h, hbx, counts, gstart, gend, Btb);
    k_scan<<<1, 1024, 0, stream>>>(counts, rowptr, cursor);
    k_scatter<<<(E2 + 255) / 256, 256, 0, stream>>>(ei, cursor, csr);

    for (int l = 0; l < 3; l++) {
        k_gemm_att<<<dim3(4, (N_NODES + 31) / 32), 256, 0, stream>>>(
            hbx, Btb + (size_t)l * 512 * 128,
            att_s + l * NHEAD * 128, att_d + l * NHEAD * 128,
            hb, a_src, a_dst);
        k_agg<<<(N_NODES + 3) / 4, 256, 0, stream>>>((const uint4*)hb, rowptr, counts, csr,
                                           a_src, a_dst,
                                           biases + l * HIDDEN, ln_g + l * HIDDEN,
                                           ln_b + l * HIDDEN, h, hbx,
                                           batch, gstart, gend, gout, (l == 2) ? 1 : 0);
    }
}

// Round 10
// 269.705 us; speedup vs baseline: 1.3882x; 1.3644x over previous
//
#include <hip/hip_runtime.h>
#include <math.h>

#define N_NODES 10000
#define N_EDGES 160000
#define E2 (N_EDGES + N_NODES)
#define HIDDEN 128
#define NHEAD 4
#define NB 32
#define LN_EPS 1e-5f

// flat-tid region boundaries for k_pre
#define T_INPUT (N_NODES * HIDDEN)                 // 1,280,000
#define T_HIST  (T_INPUT + N_EDGES)                // +160,000
#define T_CONV  (T_HIST + 3 * 512 * 128)           // +196,608
#define T_BOUND (T_CONV + N_NODES)                 // +10,000
#define T_TOTAL T_BOUND

typedef __attribute__((ext_vector_type(8))) short bf16x8;
typedef __attribute__((ext_vector_type(4))) float f32x4;

__device__ __forceinline__ unsigned short f2bf(float f) {
    unsigned int u = __float_as_uint(f);
    u += 0x7fffu + ((u >> 16) & 1u);       // RNE
    return (unsigned short)(u >> 16);
}
__device__ __forceinline__ float bf2f_lo(unsigned int u) { return __uint_as_float(u << 16); }
__device__ __forceinline__ float bf2f_hi(unsigned int u) { return __uint_as_float(u & 0xffff0000u); }

// ---------------- fused preamble: input proj + edge hist + weight conv + bounds ----
__global__ __launch_bounds__(256) void k_pre(const float* __restrict__ x,
                                             const float* __restrict__ W,
                                             const float* __restrict__ b,
                                             const int* __restrict__ ei,
                                             const int* __restrict__ batch,
                                             const float* __restrict__ Ws,
                                             float* __restrict__ h,
                                             unsigned short* __restrict__ hb,
                                             int* counts, int* gstart, int* gend,
                                             unsigned short* __restrict__ Btb) {
    int t = blockIdx.x * blockDim.x + threadIdx.x;
    if (t < T_INPUT) {
        int n = t >> 7, c = t & 127;
        float s = b[c];
        #pragma unroll
        for (int k = 0; k < 5; k++) s += x[n * 5 + k] * W[k * HIDDEN + c];
        float r = fmaxf(s, 0.f);
        h[t] = r;
        hb[t] = f2bf(r);
    } else if (t < T_HIST) {
        int e = t - T_INPUT;
        atomicAdd(&counts[ei[N_EDGES + e]], 1);
    } else if (t < T_CONV) {
        int i = t - T_HIST;
        int l = i >> 16, rem = i & 65535;
        int n = rem >> 7, k = rem & 127;
        Btb[i] = f2bf(Ws[l * 65536 + k * 512 + n]);
    } else if (t < T_BOUND) {
        int n = t - T_CONV;
        int bb = batch[n];
        if (n == 0 || batch[n - 1] != bb) gstart[bb] = n;
        if (n == N_NODES - 1 || batch[n + 1] != bb) gend[bb] = n + 1;
    }
}

// ---------------- prefix scan (adds +1 self-loop per node) ----------------
__global__ void k_scan(const int* __restrict__ counts, int* rowptr, int* cursor) {
    __shared__ int sums[1024];
    int t = threadIdx.x;
    const int per = 10;
    int base = t * per;
    int loc[per];
    int s = 0;
    for (int i = 0; i < per; i++) {
        int idx = base + i;
        int v = (idx < N_NODES) ? counts[idx] + 1 : 0;   // +1 = self-loop
        loc[i] = s; s += v;
    }
    sums[t] = s;
    __syncthreads();
    for (int off = 1; off < 1024; off <<= 1) {
        int v = (t >= off) ? sums[t - off] : 0;
        __syncthreads();
        sums[t] += v;
        __syncthreads();
    }
    int prefix = (t > 0) ? sums[t - 1] : 0;
    for (int i = 0; i < per; i++) {
        int idx = base + i;
        if (idx < N_NODES) { int r = prefix + loc[i]; rowptr[idx] = r; cursor[idx] = r; }
    }
    if (t == 1023) rowptr[N_NODES] = sums[1023];
}

__global__ void k_scatter(const int* __restrict__ ei, int* cursor, int* csr_src) {
    int e = blockIdx.x * blockDim.x + threadIdx.x;
    if (e < N_EDGES) {
        int s = ei[e], d = ei[N_EDGES + e];
        int pos = atomicAdd(&cursor[d], 1);
        csr_src[pos] = s;
    } else if (e < E2) {
        int n = e - N_EDGES;
        int pos = atomicAdd(&cursor[n], 1);
        csr_src[pos] = n;
    }
}

// ---------------- MFMA GEMM + fused attention scores -------------------------
__global__ __launch_bounds__(256) void k_gemm_att(const unsigned short* __restrict__ Ab,
                                                  const unsigned short* __restrict__ Bt,
                                                  const float* __restrict__ ws,
                                                  const float* __restrict__ wd,
                                                  unsigned short* __restrict__ Cb,
                                                  float* __restrict__ a_src,
                                                  float* __restrict__ a_dst) {
    int wave = threadIdx.x >> 6, lane = threadIdx.x & 63;
    int q = lane >> 4, u = lane & 15;
    int h = blockIdx.x;
    int rowgrp = wave & 1, colhalf = wave >> 1;
    int mbase = blockIdx.y * 32 + rowgrp * 16;
    int colbase = h * 128 + colhalf * 64;
    int arow = mbase + u;
    if (arow > N_NODES - 1) arow = N_NODES - 1;
    bf16x8 a[4];
    #pragma unroll
    for (int k0 = 0; k0 < 4; k0++)
        a[k0] = *(const bf16x8*)(Ab + (size_t)arow * 128 + k0 * 32 + q * 8);
    f32x4 acc[4];
    #pragma unroll
    for (int nb = 0; nb < 4; nb++) acc[nb] = (f32x4){0.f, 0.f, 0.f, 0.f};
    #pragma unroll
    for (int nb = 0; nb < 4; nb++) {
        const unsigned short* bp = Bt + (size_t)(colbase + nb * 16 + u) * 128 + q * 8;
        #pragma unroll
        for (int k0 = 0; k0 < 4; k0++) {
            bf16x8 bfr = *(const bf16x8*)(bp + k0 * 32);
            acc[nb] = __builtin_amdgcn_mfma_f32_16x16x32_bf16(a[k0], bfr, acc[nb], 0, 0, 0);
        }
    }
    #pragma unroll
    for (int nb = 0; nb < 4; nb++) {
        int col = colbase + nb * 16 + u;
        #pragma unroll
        for (int r = 0; r < 4; r++) {
            int row = mbase + q * 4 + r;
            if (row < N_NODES) Cb[(size_t)row * 512 + col] = f2bf(acc[nb][r]);
        }
    }
    float ps[4] = {}, pd[4] = {};
    #pragma unroll
    for (int nb = 0; nb < 4; nb++) {
        int cl = colhalf * 64 + nb * 16 + u;
        float wsv = ws[h * 128 + cl], wdv = wd[h * 128 + cl];
        #pragma unroll
        for (int r = 0; r < 4; r++) { ps[r] += acc[nb][r] * wsv; pd[r] += acc[nb][r] * wdv; }
    }
    #pragma unroll
    for (int d = 1; d < 16; d <<= 1) {
        #pragma unroll
        for (int r = 0; r < 4; r++) {
            ps[r] += __shfl_xor(ps[r], d);
            pd[r] += __shfl_xor(pd[r], d);
        }
    }
    __shared__ float ls[2][2][16], ldd[2][2][16];
    if (u == 0) {
        #pragma unroll
        for (int r = 0; r < 4; r++) {
            ls[rowgrp][colhalf][q * 4 + r] = ps[r];
            ldd[rowgrp][colhalf][q * 4 + r] = pd[r];
        }
    }
    __syncthreads();
    if (colhalf == 0 && lane < 16) {
        int row = mbase + lane;
        if (row < N_NODES) {
            a_src[row * 4 + h] = ls[rowgrp][0][lane] + ls[rowgrp][1][lane];
            a_dst[row * 4 + h] = ldd[rowgrp][0][lane] + ldd[rowgrp][1][lane];
        }
    }
}

// ---------------- fused aggregate + head-mean + LN + relu + residual ----------------
// r7 edge loop + 2-deep software pipeline: prefetch edge i+1's gather while
// processing edge i. Register-lean (one extra uint4 + float live).
__global__ __launch_bounds__(256) void k_agg(const uint4* __restrict__ hb4,
                                             const int* __restrict__ rowptr,
                                             const int* __restrict__ csr,
                                             const float* __restrict__ a_src,
                                             const float* __restrict__ a_dst,
                                             const float* __restrict__ bias,
                                             const float* __restrict__ lng,
                                             const float* __restrict__ lnb,
                                             float* __restrict__ h,
                                             unsigned short* __restrict__ hbn) {
    int wave = threadIdx.x >> 6;
    int lane = threadIdx.x & 63;
    int n = blockIdx.x * 4 + wave;
    if (n >= N_NODES) return;
    int hl = lane >> 4;
    int pos = lane & 15;
    int off = rowptr[n];
    int deg = rowptr[n + 1] - off;
    float adn = a_dst[n * 4 + hl];
    float m = -INFINITY, denom = 0.f;
    float o[8] = {};
    for (int base = 0; base < deg; base += 64) {
        int cnt = min(64, deg - base);
        int s = (lane < cnt) ? csr[off + base + lane] : 0;
        // prime the pipeline with edge 0
        int si = __shfl(s, 0);
        uint4 u = hb4[(size_t)si * 64 + lane];
        float av = a_src[si * 4 + hl];
        for (int i = 0; i < cnt; i++) {
            // prefetch edge i+1 (duplicate of last edge on final iter; harmless)
            int inext = (i + 1 < cnt) ? i + 1 : i;
            int sj = __shfl(s, inext);
            uint4 un = hb4[(size_t)sj * 64 + lane];
            float an = a_src[sj * 4 + hl];
            // process edge i
            float t = av + adn;
            float e = t > 0.f ? t : 0.2f * t;
            float nm = fmaxf(m, e);
            float sc = __expf(m - nm);           // first edge: exp(-inf) = 0
            float p = __expf(e - nm);
            denom = denom * sc + p;
            o[0] = o[0] * sc + p * bf2f_lo(u.x);
            o[1] = o[1] * sc + p * bf2f_hi(u.x);
            o[2] = o[2] * sc + p * bf2f_lo(u.y);
            o[3] = o[3] * sc + p * bf2f_hi(u.y);
            o[4] = o[4] * sc + p * bf2f_lo(u.z);
            o[5] = o[5] * sc + p * bf2f_hi(u.z);
            o[6] = o[6] * sc + p * bf2f_lo(u.w);
            o[7] = o[7] * sc + p * bf2f_hi(u.w);
            m = nm;
            u = un; av = an;
        }
    }
    float inv = 1.f / (denom + 1e-16f);
    #pragma unroll
    for (int k = 0; k < 8; k++) o[k] *= inv;
    #pragma unroll
    for (int k = 0; k < 8; k++) {
        o[k] += __shfl_xor(o[k], 16);
        o[k] += __shfl_xor(o[k], 32);
    }
    float v[8], sv = 0.f, sq = 0.f;
    #pragma unroll
    for (int k = 0; k < 8; k++) {
        float b = bias[8 * pos + k];
        v[k] = 0.25f * o[k] + b;
        sv += v[k]; sq += v[k] * v[k];
    }
    #pragma unroll
    for (int d = 8; d > 0; d >>= 1) {
        sv += __shfl_xor(sv, d);
        sq += __shfl_xor(sq, d);
    }
    float mu = sv * (1.f / 128.f);
    float var = sq * (1.f / 128.f) - mu * mu;
    float rs = rsqrtf(var + LN_EPS);
    if (hl == 0) {
        float* hrow = h + (size_t)n * 128 + 8 * pos;
        float4 old0 = *(const float4*)(hrow);
        float4 old1 = *(const float4*)(hrow + 4);
        float r[8];
        #pragma unroll
        for (int k = 0; k < 8; k++) {
            float y = (v[k] - mu) * rs * lng[8 * pos + k] + lnb[8 * pos + k];
            r[k] = fmaxf(y, 0.f);
        }
        float w[8] = {r[0] + old0.x, r[1] + old0.y, r[2] + old0.z, r[3] + old0.w,
                      r[4] + old1.x, r[5] + old1.y, r[6] + old1.z, r[7] + old1.w};
        *(float4*)(hrow) = make_float4(w[0], w[1], w[2], w[3]);
        *(float4*)(hrow + 4) = make_float4(w[4], w[5], w[6], w[7]);
        ushort4 p0, p1;
        p0.x = f2bf(w[0]); p0.y = f2bf(w[1]); p0.z = f2bf(w[2]); p0.w = f2bf(w[3]);
        p1.x = f2bf(w[4]); p1.y = f2bf(w[5]); p1.z = f2bf(w[6]); p1.w = f2bf(w[7]);
        unsigned short* hbrow = hbn + (size_t)n * 128 + 8 * pos;
        *(ushort4*)(hbrow) = p0;
        *(ushort4*)(hbrow + 4) = p1;
    }
}

// ---------------- graph mean pool (boundary-only atomics, pre-divided) ------------
#define POOL_CHUNK 32
__global__ __launch_bounds__(128) void k_pool_sum(const float* __restrict__ h,
                                                  const int* __restrict__ batch,
                                                  const int* __restrict__ gstart,
                                                  const int* __restrict__ gend,
                                                  float* __restrict__ gout) {
    int n0 = blockIdx.x * POOL_CHUNK;
    int c = threadIdx.x;
    int nend = min(n0 + POOL_CHUNK, N_NODES);
    if (n0 >= N_NODES) return;
    int cur = batch[n0];
    float acc = 0.f;
    for (int n = n0; n < nend; n++) {
        int b = batch[n];
        if (b != cur) {
            float inv = 1.f / (float)max(gend[cur] - gstart[cur], 1);
            atomicAdd(&gout[cur * HIDDEN + c], acc * inv);
            acc = 0.f; cur = b;
        }
        acc += h[(size_t)n * HIDDEN + c];
    }
    float inv = 1.f / (float)max(gend[cur] - gstart[cur], 1);
    atomicAdd(&gout[cur * HIDDEN + c], acc * inv);
}

extern "C" void kernel_launch(void* const* d_in, const int* in_sizes, int n_in,
                              void* d_out, int out_size, void* d_ws, size_t ws_size,
                              hipStream_t stream) {
    const float* x      = (const float*)d_in[0];
    const int*   ei     = (const int*)d_in[1];
    const int*   batch  = (const int*)d_in[2];
    const float* node_W = (const float*)d_in[3];
    const float* node_b = (const float*)d_in[4];
    const float* Ws     = (const float*)d_in[5];
    const float* att_s  = (const float*)d_in[6];
    const float* att_d  = (const float*)d_in[7];
    const float* biases = (const float*)d_in[8];
    const float* ln_g   = (const float*)d_in[9];
    const float* ln_b   = (const float*)d_in[10];

    float* out = (float*)d_out;
    float* h = out;
    float* gout = out + (size_t)N_NODES * HIDDEN;

    char* w = (char*)d_ws;
    auto carve = [&](size_t bytes) {
        void* p = (void*)w;
        w += (bytes + 255) & ~(size_t)255;
        return p;
    };
    int* rowptr  = (int*)carve((N_NODES + 1) * sizeof(int));
    int* cursor  = (int*)carve(N_NODES * sizeof(int));
    int* counts  = (int*)carve(N_NODES * sizeof(int));
    int* csr     = (int*)carve((E2 + 16) * sizeof(int));
    int* gstart  = (int*)carve(NB * sizeof(int));
    int* gend    = (int*)carve(NB * sizeof(int));
    float* a_src = (float*)carve((size_t)N_NODES * NHEAD * sizeof(float));
    float* a_dst = (float*)carve((size_t)N_NODES * NHEAD * sizeof(float));
    unsigned short* hb  = (unsigned short*)carve((size_t)N_NODES * 512 * sizeof(unsigned short));
    unsigned short* hbx = (unsigned short*)carve((size_t)N_NODES * HIDDEN * sizeof(unsigned short));
    unsigned short* Btb = (unsigned short*)carve((size_t)3 * 512 * 128 * sizeof(unsigned short));

    hipMemsetAsync(counts, 0, N_NODES * sizeof(int), stream);
    hipMemsetAsync(gout, 0, NB * HIDDEN * sizeof(float), stream);

    k_pre<<<(T_TOTAL + 255) / 256, 256, 0, stream>>>(x, node_W, node_b, ei, batch, Ws,
                                                     h, hbx, counts, gstart, gend, Btb);
    k_scan<<<1, 1024, 0, stream>>>(counts, rowptr, cursor);
    k_scatter<<<(E2 + 255) / 256, 256, 0, stream>>>(ei, cursor, csr);

    for (int l = 0; l < 3; l++) {
        k_gemm_att<<<dim3(4, (N_NODES + 31) / 32), 256, 0, stream>>>(
            hbx, Btb + (size_t)l * 512 * 128,
            att_s + l * NHEAD * 128, att_d + l * NHEAD * 128,
            hb, a_src, a_dst);
        k_agg<<<(N_NODES + 3) / 4, 256, 0, stream>>>((const uint4*)hb, rowptr, csr,
                                           a_src, a_dst,
                                           biases + l * HIDDEN, ln_g + l * HIDDEN,
                                           ln_b + l * HIDDEN, h, hbx);
    }
    k_pool_sum<<<(N_NODES + POOL_CHUNK - 1) / POOL_CHUNK, 128, 0, stream>>>(
        h, batch, gstart, gend, gout);
}